// Round 19
// baseline (326.735 us; speedup 1.0000x reference)
//
#include <hip/hip_runtime.h>
#include <cstdint>

#define B_SZ 1024
#define NTHR 640

// ---------------------------------------------------------------------------
// Threefry-2x32 (20 rounds), exactly as jax._src.prng.threefry2x32.
// ---------------------------------------------------------------------------
__host__ __device__ inline void tf2x32(uint32_t k0, uint32_t k1,
                                       uint32_t x0, uint32_t x1,
                                       uint32_t& o0, uint32_t& o1) {
  uint32_t ks2 = 0x1BD11BDAu ^ k0 ^ k1;
#define TF_RND(r) { x0 += x1; x1 = (x1 << (r)) | (x1 >> (32 - (r))); x1 ^= x0; }
  x0 += k0; x1 += k1;
  TF_RND(13) TF_RND(15) TF_RND(26) TF_RND(6)
  x0 += k1; x1 += ks2 + 1u;
  TF_RND(17) TF_RND(29) TF_RND(16) TF_RND(24)
  x0 += ks2; x1 += k0 + 2u;
  TF_RND(13) TF_RND(15) TF_RND(26) TF_RND(6)
  x0 += k0; x1 += k1 + 3u;
  TF_RND(17) TF_RND(29) TF_RND(16) TF_RND(24)
  x0 += k1; x1 += ks2 + 4u;
  TF_RND(13) TF_RND(15) TF_RND(26) TF_RND(6)
  x0 += ks2; x1 += k0 + 5u;
#undef TF_RND
  o0 = x0; o1 = x1;
}

// XLA ErfInv f32 expansion, identical coefficients.
__device__ inline float erfinv_f32(float x) {
  float w = -log1pf(-x * x);
  float p;
  if (w < 5.0f) {
    w -= 2.5f;
    p = 2.81022636e-08f;
    p = fmaf(p, w, 3.43273939e-07f);
    p = fmaf(p, w, -3.5233877e-06f);
    p = fmaf(p, w, -4.39150654e-06f);
    p = fmaf(p, w, 0.00021858087f);
    p = fmaf(p, w, -0.00125372503f);
    p = fmaf(p, w, -0.00417768164f);
    p = fmaf(p, w, 0.246640727f);
    p = fmaf(p, w, 1.50140941f);
  } else {
    w = sqrtf(w) - 3.0f;
    p = -0.000200214257f;
    p = fmaf(p, w, 0.000100950558f);
    p = fmaf(p, w, 0.00134934322f);
    p = fmaf(p, w, -0.00367342844f);
    p = fmaf(p, w, 0.00573950773f);
    p = fmaf(p, w, -0.0076224613f);
    p = fmaf(p, w, 0.00943887047f);
    p = fmaf(p, w, 1.00167406f);
    p = fmaf(p, w, 2.83297682f);
  }
  return p * x;
}

__device__ inline float jax_normal_pt(uint32_t k0, uint32_t k1, uint32_t e) {
  uint32_t o0, o1;
  tf2x32(k0, k1, 0u, e, o0, o1);
  uint32_t bits = o0 ^ o1;
  float f = __uint_as_float((bits >> 9) | 0x3f800000u) - 1.0f;
  const float LO = -0.99999994f;
  float u = fmaxf(LO, fmaf(f, 2.0f, LO));
  return 1.41421356f * erfinv_f32(u);
}

struct OodArgs {
  const float* x;
  const float* noise_w;
  const float* noise_b;
  const float* feat_w[5];
  const float* feat_b[5];
  const float* mu_w[5];
  const float* mu_b[5];
  const float* std_w[5];
  const float* std_b[5];
  float* mean_out[5];
  float* std_out[5];
  float* scores;   // ws[0..5120)
  float* gws;      // ws + 5120: per (b,I) 560 floats: g[540] | rs[20]
  uint32_t fk0[5], fk1[5];
};

// Padded image buffers: 34 rows x pitch 35 per channel.  Phase-3 lane banks:
// addr = 35*ss + c -> bank 3*ss mod 32, all-distinct for ss in [0,32).
#define PITCH 35
#define CHSZ  (34 * PITCH)   // 1190
#define XSZ   (3 * CHSZ)     // 3570

// Kernel A LDS (floats)
#define A_XP   0             // 3570
#define A_XI   3570          // 3570
#define A_NW   7140          // 81
#define A_NB   7221          // 3
#define A_SMEM 7224

// ---------------------------------------------------------------------------
// KERNEL A (phases 1-3): 640 thr = 20 groups x 32 lanes, 1 row + 1 k per
// lane, b32 conflict-free; phase 2 register-staged (zero bank conflicts,
// R17); launch bounds (640,4) -> ~64 VGPR, no spill (R18).
// b = blockIdx.y, stage = blockIdx.x (interleaved dispatch).
// ---------------------------------------------------------------------------
template<int S, int STRIDE>
__device__ __forceinline__ void stageA(const OodArgs& A_, float* smem, int i) {
  constexpr int Wd = 32 / STRIDE;
  const int b = blockIdx.y;
  const int t = threadIdx.x;

  float* s_xp = smem + A_XP;
  float* s_xi = smem + A_XI;
  float* s_nw = smem + A_NW;
  float* s_nb = smem + A_NB;

  // ---- phase 1: zero padded buffers (float4), load x[b] interior ----
  {
    float4 z; z.x = z.y = z.z = z.w = 0.0f;
    float4* z4 = (float4*)smem;                  // smem is 16B-aligned
    for (int p = t; p < (2 * XSZ) / 4; p += NTHR) z4[p] = z;
  }
  if (t < 81) s_nw[t] = A_.noise_w[81 * i + t];
  if (t < 3)  s_nb[t] = A_.noise_b[3 * i + t];
  __syncthreads();
  const float* xb = A_.x + (size_t)b * 3072;
  for (int p = t; p < 3072; p += NTHR) {
    int ci = p >> 10, rr = p & 1023, yy = rr >> 5, xx = rr & 31;
    s_xp[ci * CHSZ + (yy + 1) * PITCH + (xx + 1)] = xb[p];
  }
  __syncthreads();

  // ---- phase 2: xi = x + conv3x3(x, noise_w); 384 threads x 8-px runs ----
  if (t < 384) {
    const int co = t >> 7;            // 0..2
    const int r  = t & 127;
    const int y  = r >> 2;            // 0..31
    const int xs = (r & 3) * 8;       // 0,8,16,24
    const float nb = s_nb[co];
    float acc[8];
    #pragma unroll
    for (int j = 0; j < 8; ++j) acc[j] = nb;
    #pragma unroll
    for (int c2 = 0; c2 < 3; ++c2) {
      #pragma unroll
      for (int dy = 0; dy < 3; ++dy) {
        const float w0 = s_nw[co * 27 + c2 * 9 + dy * 3 + 0];
        const float w1 = s_nw[co * 27 + c2 * 9 + dy * 3 + 1];
        const float w2 = s_nw[co * 27 + c2 * 9 + dy * 3 + 2];
        const int ra = c2 * CHSZ + (y + dy) * PITCH + xs;
        float R[10];
        #pragma unroll
        for (int u = 0; u < 10; ++u) R[u] = s_xp[ra + u];
        #pragma unroll
        for (int j = 0; j < 8; ++j) {
          acc[j] = fmaf(w0, R[j],     acc[j]);
          acc[j] = fmaf(w1, R[j + 1], acc[j]);
          acc[j] = fmaf(w2, R[j + 2], acc[j]);
        }
      }
    }
    const int ob = co * CHSZ + (y + 1) * PITCH + (xs + 1);
    #pragma unroll
    for (int j = 0; j < 8; ++j)
      s_xi[ob + j] = acc[j] + s_xp[ob + j];
  }
  __syncthreads();

  // ---- phase 3: g[wh][k][ci*9+q] = sum_s w[k,s]*xi[ci,patch(s,q)] ----
  const int G  = t >> 5;           // 0..19
  const int ss = t & 31;           // row / spatial sub
  const int wh = G & 1;
  const int kk = G >> 1;           // 0..9
  const float* wsrc = (wh ? A_.std_w[i] : A_.mu_w[i]) + kk * S;
  float* gdst = A_.gws + (size_t)(b * 5 + i) * 560;

#define REDUCE_WRITE(ci_) { \
    _Pragma("unroll") \
    for (int j = 0; j < 9; ++j) { \
      float v = acc[j]; \
      v += __shfl_xor(v,  1, 64); \
      v += __shfl_xor(v,  2, 64); \
      v += __shfl_xor(v,  4, 64); \
      v += __shfl_xor(v,  8, 64); \
      v += __shfl_xor(v, 16, 64); \
      acc[j] = v; \
    } \
    if ((ci_) == 0) { \
      rs += __shfl_xor(rs, 1, 64); rs += __shfl_xor(rs, 2, 64); \
      rs += __shfl_xor(rs, 4, 64); rs += __shfl_xor(rs, 8, 64); \
      rs += __shfl_xor(rs, 16, 64); \
    } \
    if (ss == 0) { \
      _Pragma("unroll") \
      for (int j = 0; j < 9; ++j) \
        gdst[(wh * 10 + kk) * 27 + (ci_) * 9 + j] = acc[j]; \
      if ((ci_) == 0) gdst[540 + wh * 10 + kk] = rs; \
    } }

  if constexpr (STRIDE == 1) {
    // lane owns output row ss; padded rows ss..ss+2 at rb + u*PITCH.
    const float* wr = wsrc + ss * 32;
    const int rbase0 = ss * PITCH;
    #pragma unroll
    for (int ci = 0; ci < 3; ++ci) {
      const int rb = ci * CHSZ + rbase0;
      float acc[9];
      #pragma unroll
      for (int j = 0; j < 9; ++j) acc[j] = 0.0f;
      float rs = 0.0f;
      float Av[3], Bv[3], Cv[3];
      #pragma unroll
      for (int u = 0; u < 3; ++u) {
        Av[u] = s_xi[rb + u * PITCH + 0];
        Bv[u] = s_xi[rb + u * PITCH + 1];
      }

#define WCOMP(V, L) ((L) == 0 ? (V).x : (L) == 1 ? (V).y : (L) == 2 ? (V).z : (V).w)
#define STEP(X, P, Q, R, W0) { \
    _Pragma("unroll") \
    for (int u = 0; u < 3; ++u) R[u] = s_xi[rb + u * PITCH + (X) + 2]; \
    const float w0c = WCOMP(W0, (X) & 3); \
    _Pragma("unroll") \
    for (int dy = 0; dy < 3; ++dy) { \
      acc[dy*3+0] = fmaf(w0c, P[dy], acc[dy*3+0]); \
      acc[dy*3+1] = fmaf(w0c, Q[dy], acc[dy*3+1]); \
      acc[dy*3+2] = fmaf(w0c, R[dy], acc[dy*3+2]); \
    } \
    if (ci == 0) rs += w0c; \
  }
#define G4_0(c) { const float4 w0 = *(const float4*)(wr + (c)); \
    STEP((c)+0, Av, Bv, Cv, w0) STEP((c)+1, Bv, Cv, Av, w0) \
    STEP((c)+2, Cv, Av, Bv, w0) STEP((c)+3, Av, Bv, Cv, w0) }
#define G4_1(c) { const float4 w0 = *(const float4*)(wr + (c)); \
    STEP((c)+0, Bv, Cv, Av, w0) STEP((c)+1, Cv, Av, Bv, w0) \
    STEP((c)+2, Av, Bv, Cv, w0) STEP((c)+3, Bv, Cv, Av, w0) }
#define G4_2(c) { const float4 w0 = *(const float4*)(wr + (c)); \
    STEP((c)+0, Cv, Av, Bv, w0) STEP((c)+1, Av, Bv, Cv, w0) \
    STEP((c)+2, Bv, Cv, Av, w0) STEP((c)+3, Cv, Av, Bv, w0) }

      G4_0(0) G4_1(4) G4_2(8) G4_0(12) G4_1(16) G4_2(20) G4_0(24) G4_1(28)

#undef G4_0
#undef G4_1
#undef G4_2
#undef STEP
#undef WCOMP
      REDUCE_WRITE(ci)
    }
  } else {
    constexpr int PER = (S >= 32) ? (S / 32) : 1;   // 8 / 2 / 1
    #pragma unroll
    for (int ci = 0; ci < 3; ++ci) {
      float acc[9];
      #pragma unroll
      for (int j = 0; j < 9; ++j) acc[j] = 0.0f;
      float rs = 0.0f;
      if (S >= 32 || ss < S) {
        #pragma unroll
        for (int u = 0; u < PER; ++u) {
          const int s  = (S >= 32) ? (ss * PER + u) : ss;
          const int yo = s / Wd, xo = s % Wd;
          const float wx = wsrc[s];
          #pragma unroll
          for (int dy = 0; dy < 3; ++dy) {
            const int ba = ci * CHSZ + (yo * STRIDE + dy + 1) * PITCH + (xo * STRIDE + 1);
            #pragma unroll
            for (int dx = 0; dx < 3; ++dx)
              acc[dy * 3 + dx] = fmaf(wx, s_xi[ba + dx], acc[dy * 3 + dx]);
          }
          if (ci == 0) rs += wx;
        }
      }
      REDUCE_WRITE(ci)
    }
  }
#undef REDUCE_WRITE
}

__global__ __launch_bounds__(NTHR, 4)
void ood_a_s1(OodArgs A_) {
  __shared__ __align__(16) float smem[A_SMEM];
  stageA<1024, 1>(A_, smem, blockIdx.x);          // stages 0,1
}

__global__ __launch_bounds__(NTHR, 4)
void ood_a_sN(OodArgs A_) {
  __shared__ __align__(16) float smem[A_SMEM];
  switch (blockIdx.x) {
    case 0:  stageA<256, 2>(A_, smem, 2); break;
    case 1:  stageA< 64, 4>(A_, smem, 3); break;
    default: stageA< 16, 8>(A_, smem, 4); break;
  }
}

// ---------------------------------------------------------------------------
// KERNEL B: phases 4a/4b/5.  640 threads; phase 4b assigns ONE class per
// wave (10 waves <-> 10 classes) halving the per-lane RNG critical path at
// C=512; grid (5, B) interleaves heavy and light stages in dispatch order
// (kills the all-C=512-at-the-end occupancy tail seen in R18).
// Per-class lane sums and reduce trees identical -> bit-identical results.
// ---------------------------------------------------------------------------
template<int I, int C>
__device__ __forceinline__ void stageB(const OodArgs& A_, float* smem) {
  const int b = blockIdx.y;
  const int t = threadIdx.x;

  float* s_g   = smem;             // 540
  float* s_rs  = smem + 540;       // 20
  float* s_std = smem + 560;       // 10*C
  float* s_pt  = smem + 560 + 10 * C;  // 10
  int*   s_idx = (int*)(smem + 570 + 10 * C);

  const float* feat_w = A_.feat_w[I];
  const float* feat_b = A_.feat_b[I];
  const uint32_t fk0 = A_.fk0[I], fk1 = A_.fk1[I];

  const float* gsrc = A_.gws + (size_t)(b * 5 + I) * 560;
  for (int p = t; p < 560; p += NTHR) smem[p] = gsrc[p];
  __syncthreads();

  // ---- phase 4a: s_std[k*C+c] for all classes ----
  for (int v = t; v < 10 * C; v += NTHR) {
    const int k2 = v / C; const int c = v - k2 * C;
    const float* fw = feat_w + c * 27;
    float a2 = 0.0f;
    #pragma unroll
    for (int j = 0; j < 27; ++j) a2 = fmaf(s_g[(10 + k2) * 27 + j], fw[j], a2);
    a2 = fmaf(feat_b[c], s_rs[10 + k2], a2) + A_.std_b[I][k2];
    s_std[v] = a2;
  }
  __syncthreads();

  // ---- phase 4b: mahal — wave g handles class g (10 waves, 10 classes) ----
  {
    const int g  = t >> 6;     // 0..9
    const int ln = t & 63;
    float m0 = 0.0f;
    for (int c = ln; c < C; c += 64) {
      const float sd  = s_std[g * C + c];
      const float eps = jax_normal_pt(fk0, fk1, (uint32_t)((b * 10 + g) * C + c));
      m0 = fmaf(sd * sd, eps * eps, m0);
    }
    #pragma unroll
    for (int off = 32; off > 0; off >>= 1) m0 += __shfl_down(m0, off, 64);
    if (ln == 0) s_pt[g] = m0;
  }
  __syncthreads();
  if (t == 0) {
    float best = -INFINITY; int bi = 0;
    #pragma unroll
    for (int k2 = 0; k2 < 10; ++k2) {
      float m = -0.5f * s_pt[k2];
      if (m > best) { best = m; bi = k2; }
    }
    A_.scores[b * 5 + I] = best;
    *s_idx = bi;
  }
  __syncthreads();

  // ---- phase 5: outputs (mean recomputed for argmax class; std from LDS) --
  const int idx = *s_idx;
  for (int c = t; c < C; c += NTHR) {
    const float* fw = feat_w + c * 27;
    float a1 = 0.0f;
    #pragma unroll
    for (int j = 0; j < 27; ++j) a1 = fmaf(s_g[idx * 27 + j], fw[j], a1);
    a1 = fmaf(feat_b[c], s_rs[idx], a1) + A_.mu_b[I][idx];
    A_.mean_out[I][(size_t)b * C + c] = a1;
    A_.std_out[I][(size_t)b * C + c]  = s_std[idx * C + c];
  }
}

__global__ __launch_bounds__(NTHR)
void ood_b(OodArgs A_) {
  __shared__ float smem[571 + 5120];   // worst case C=512
  switch (blockIdx.x) {
    case 0: stageB<0,  64>(A_, smem); break;
    case 1: stageB<1,  64>(A_, smem); break;
    case 2: stageB<2, 128>(A_, smem); break;
    case 3: stageB<3, 256>(A_, smem); break;
    default: stageB<4, 512>(A_, smem); break;
  }
}

__global__ void ood_clf(const float* __restrict__ scores,  // (B,5)
                        const float* __restrict__ clf_w,   // (1,5)
                        const float* __restrict__ clf_b,   // (1,)
                        float* __restrict__ out) {         // (B,)
  int b = blockIdx.x * blockDim.x + threadIdx.x;
  if (b < B_SZ) {
    float acc = clf_b[0];
    #pragma unroll
    for (int i = 0; i < 5; ++i) acc = fmaf(scores[b * 5 + i], clf_w[i], acc);
    out[b] = acc;
  }
}

extern "C" void kernel_launch(void* const* d_in, const int* in_sizes, int n_in,
                              void* d_out, int out_size, void* d_ws, size_t ws_size,
                              hipStream_t stream) {
  (void)in_sizes; (void)n_in; (void)out_size; (void)ws_size;
  const float* clf_w = (const float*)d_in[33];
  const float* clf_b = (const float*)d_in[34];
  float* out = (float*)d_out;
  float* ws  = (float*)d_ws;   // scores[5120] | g-blobs[5120*560]

  OodArgs A_;
  A_.x       = (const float*)d_in[0];
  A_.noise_w = (const float*)d_in[1];
  A_.noise_b = (const float*)d_in[2];
  const size_t NMEAN = 1048576;
  const size_t moff[5] = {1024, 66560, 132096, 263168, 525312};
  for (int i = 0; i < 5; ++i) {
    A_.feat_w[i]   = (const float*)d_in[3 + 6 * i];
    A_.feat_b[i]   = (const float*)d_in[4 + 6 * i];
    A_.mu_w[i]     = (const float*)d_in[5 + 6 * i];
    A_.mu_b[i]     = (const float*)d_in[6 + 6 * i];
    A_.std_w[i]    = (const float*)d_in[7 + 6 * i];
    A_.std_b[i]    = (const float*)d_in[8 + 6 * i];
    A_.mean_out[i] = out + moff[i];
    A_.std_out[i]  = out + moff[i] + NMEAN;
    tf2x32(0u, 42u, 0u, (uint32_t)i, A_.fk0[i], A_.fk1[i]);
  }
  A_.scores = ws;
  A_.gws    = ws + 5120;

  ood_a_s1<<<dim3(2, B_SZ), NTHR, 0, stream>>>(A_);
  ood_a_sN<<<dim3(3, B_SZ), NTHR, 0, stream>>>(A_);
  ood_b<<<dim3(5, B_SZ), NTHR, 0, stream>>>(A_);
  ood_clf<<<(B_SZ + 255) / 256, 256, 0, stream>>>(A_.scores, clf_w, clf_b, out);
}

// Round 20
// 278.632 us; speedup vs baseline: 1.1726x; 1.1726x over previous
//
#include <hip/hip_runtime.h>
#include <cstdint>

#define B_SZ 1024
#define NTHR 640

// ---------------------------------------------------------------------------
// Threefry-2x32 (20 rounds), exactly as jax._src.prng.threefry2x32.
// ---------------------------------------------------------------------------
__host__ __device__ inline void tf2x32(uint32_t k0, uint32_t k1,
                                       uint32_t x0, uint32_t x1,
                                       uint32_t& o0, uint32_t& o1) {
  uint32_t ks2 = 0x1BD11BDAu ^ k0 ^ k1;
#define TF_RND(r) { x0 += x1; x1 = (x1 << (r)) | (x1 >> (32 - (r))); x1 ^= x0; }
  x0 += k0; x1 += k1;
  TF_RND(13) TF_RND(15) TF_RND(26) TF_RND(6)
  x0 += k1; x1 += ks2 + 1u;
  TF_RND(17) TF_RND(29) TF_RND(16) TF_RND(24)
  x0 += ks2; x1 += k0 + 2u;
  TF_RND(13) TF_RND(15) TF_RND(26) TF_RND(6)
  x0 += k0; x1 += k1 + 3u;
  TF_RND(17) TF_RND(29) TF_RND(16) TF_RND(24)
  x0 += k1; x1 += ks2 + 4u;
  TF_RND(13) TF_RND(15) TF_RND(26) TF_RND(6)
  x0 += ks2; x1 += k0 + 5u;
#undef TF_RND
  o0 = x0; o1 = x1;
}

// XLA ErfInv f32 expansion, identical coefficients.
__device__ inline float erfinv_f32(float x) {
  float w = -log1pf(-x * x);
  float p;
  if (w < 5.0f) {
    w -= 2.5f;
    p = 2.81022636e-08f;
    p = fmaf(p, w, 3.43273939e-07f);
    p = fmaf(p, w, -3.5233877e-06f);
    p = fmaf(p, w, -4.39150654e-06f);
    p = fmaf(p, w, 0.00021858087f);
    p = fmaf(p, w, -0.00125372503f);
    p = fmaf(p, w, -0.00417768164f);
    p = fmaf(p, w, 0.246640727f);
    p = fmaf(p, w, 1.50140941f);
  } else {
    w = sqrtf(w) - 3.0f;
    p = -0.000200214257f;
    p = fmaf(p, w, 0.000100950558f);
    p = fmaf(p, w, 0.00134934322f);
    p = fmaf(p, w, -0.00367342844f);
    p = fmaf(p, w, 0.00573950773f);
    p = fmaf(p, w, -0.0076224613f);
    p = fmaf(p, w, 0.00943887047f);
    p = fmaf(p, w, 1.00167406f);
    p = fmaf(p, w, 2.83297682f);
  }
  return p * x;
}

__device__ inline float jax_normal_pt(uint32_t k0, uint32_t k1, uint32_t e) {
  uint32_t o0, o1;
  tf2x32(k0, k1, 0u, e, o0, o1);
  uint32_t bits = o0 ^ o1;
  float f = __uint_as_float((bits >> 9) | 0x3f800000u) - 1.0f;
  const float LO = -0.99999994f;
  float u = fmaxf(LO, fmaf(f, 2.0f, LO));
  return 1.41421356f * erfinv_f32(u);
}

struct OodArgs {
  const float* x;
  const float* noise_w;
  const float* noise_b;
  const float* feat_w[5];
  const float* feat_b[5];
  const float* mu_w[5];
  const float* mu_b[5];
  const float* std_w[5];
  const float* std_b[5];
  float* mean_out[5];
  float* std_out[5];
  float* scores;   // ws[0..5120)
  float* gws;      // ws + 5120: per (b,I) 560 floats: g[540] | rs[20]
  uint32_t fk0[5], fk1[5];
};

// Padded image buffers: 34 rows x pitch 35 per channel.  Phase-3 lane banks:
// addr = 35*ss + c -> bank 3*ss mod 32, all-distinct for ss in [0,32).
#define PITCH 35
#define CHSZ  (34 * PITCH)   // 1190
#define XSZ   (3 * CHSZ)     // 3570

// Kernel A LDS (floats)
#define A_XP   0             // 3570
#define A_XI   3570          // 3570
#define A_NW   7140          // 81
#define A_NB   7221          // 3
#define A_SMEM 7224

// ---------------------------------------------------------------------------
// KERNEL A (phases 1-3): 640 thr = 20 groups x 32 lanes, 1 row + 1 k per
// lane, b32 conflict-free; phase 2 register-staged (zero bank conflicts,
// R17); launch bounds (640,4) -> ~64 VGPR, no spill (R18).  Single dispatch,
// grid (B,5): same-stage blocks contiguous (I-cache hot, per R19 lesson);
// the long stride-1 groups (y=0,1) go first, strided groups backfill.
// ---------------------------------------------------------------------------
template<int S, int STRIDE>
__device__ __forceinline__ void stageA(const OodArgs& A_, float* smem, int i) {
  constexpr int Wd = 32 / STRIDE;
  const int b = blockIdx.x;
  const int t = threadIdx.x;

  float* s_xp = smem + A_XP;
  float* s_xi = smem + A_XI;
  float* s_nw = smem + A_NW;
  float* s_nb = smem + A_NB;

  // ---- phase 1: zero padded buffers (float4), load x[b] interior ----
  {
    float4 z; z.x = z.y = z.z = z.w = 0.0f;
    float4* z4 = (float4*)smem;                  // smem is 16B-aligned
    for (int p = t; p < (2 * XSZ) / 4; p += NTHR) z4[p] = z;
  }
  if (t < 81) s_nw[t] = A_.noise_w[81 * i + t];
  if (t < 3)  s_nb[t] = A_.noise_b[3 * i + t];
  __syncthreads();
  const float* xb = A_.x + (size_t)b * 3072;
  for (int p = t; p < 3072; p += NTHR) {
    int ci = p >> 10, rr = p & 1023, yy = rr >> 5, xx = rr & 31;
    s_xp[ci * CHSZ + (yy + 1) * PITCH + (xx + 1)] = xb[p];
  }
  __syncthreads();

  // ---- phase 2: xi = x + conv3x3(x, noise_w); 384 threads x 8-px runs ----
  if (t < 384) {
    const int co = t >> 7;            // 0..2
    const int r  = t & 127;
    const int y  = r >> 2;            // 0..31
    const int xs = (r & 3) * 8;       // 0,8,16,24
    const float nb = s_nb[co];
    float acc[8];
    #pragma unroll
    for (int j = 0; j < 8; ++j) acc[j] = nb;
    #pragma unroll
    for (int c2 = 0; c2 < 3; ++c2) {
      #pragma unroll
      for (int dy = 0; dy < 3; ++dy) {
        const float w0 = s_nw[co * 27 + c2 * 9 + dy * 3 + 0];
        const float w1 = s_nw[co * 27 + c2 * 9 + dy * 3 + 1];
        const float w2 = s_nw[co * 27 + c2 * 9 + dy * 3 + 2];
        const int ra = c2 * CHSZ + (y + dy) * PITCH + xs;
        float R[10];
        #pragma unroll
        for (int u = 0; u < 10; ++u) R[u] = s_xp[ra + u];
        #pragma unroll
        for (int j = 0; j < 8; ++j) {
          acc[j] = fmaf(w0, R[j],     acc[j]);
          acc[j] = fmaf(w1, R[j + 1], acc[j]);
          acc[j] = fmaf(w2, R[j + 2], acc[j]);
        }
      }
    }
    const int ob = co * CHSZ + (y + 1) * PITCH + (xs + 1);
    #pragma unroll
    for (int j = 0; j < 8; ++j)
      s_xi[ob + j] = acc[j] + s_xp[ob + j];
  }
  __syncthreads();

  // ---- phase 3: g[wh][k][ci*9+q] = sum_s w[k,s]*xi[ci,patch(s,q)] ----
  const int G  = t >> 5;           // 0..19
  const int ss = t & 31;           // row / spatial sub
  const int wh = G & 1;
  const int kk = G >> 1;           // 0..9
  const float* wsrc = (wh ? A_.std_w[i] : A_.mu_w[i]) + kk * S;
  float* gdst = A_.gws + (size_t)(b * 5 + i) * 560;

#define REDUCE_WRITE(ci_) { \
    _Pragma("unroll") \
    for (int j = 0; j < 9; ++j) { \
      float v = acc[j]; \
      v += __shfl_xor(v,  1, 64); \
      v += __shfl_xor(v,  2, 64); \
      v += __shfl_xor(v,  4, 64); \
      v += __shfl_xor(v,  8, 64); \
      v += __shfl_xor(v, 16, 64); \
      acc[j] = v; \
    } \
    if ((ci_) == 0) { \
      rs += __shfl_xor(rs, 1, 64); rs += __shfl_xor(rs, 2, 64); \
      rs += __shfl_xor(rs, 4, 64); rs += __shfl_xor(rs, 8, 64); \
      rs += __shfl_xor(rs, 16, 64); \
    } \
    if (ss == 0) { \
      _Pragma("unroll") \
      for (int j = 0; j < 9; ++j) \
        gdst[(wh * 10 + kk) * 27 + (ci_) * 9 + j] = acc[j]; \
      if ((ci_) == 0) gdst[540 + wh * 10 + kk] = rs; \
    } }

  if constexpr (STRIDE == 1) {
    // lane owns output row ss; padded rows ss..ss+2 at rb + u*PITCH.
    const float* wr = wsrc + ss * 32;
    const int rbase0 = ss * PITCH;
    #pragma unroll
    for (int ci = 0; ci < 3; ++ci) {
      const int rb = ci * CHSZ + rbase0;
      float acc[9];
      #pragma unroll
      for (int j = 0; j < 9; ++j) acc[j] = 0.0f;
      float rs = 0.0f;
      float Av[3], Bv[3], Cv[3];
      #pragma unroll
      for (int u = 0; u < 3; ++u) {
        Av[u] = s_xi[rb + u * PITCH + 0];
        Bv[u] = s_xi[rb + u * PITCH + 1];
      }

#define WCOMP(V, L) ((L) == 0 ? (V).x : (L) == 1 ? (V).y : (L) == 2 ? (V).z : (V).w)
#define STEP(X, P, Q, R, W0) { \
    _Pragma("unroll") \
    for (int u = 0; u < 3; ++u) R[u] = s_xi[rb + u * PITCH + (X) + 2]; \
    const float w0c = WCOMP(W0, (X) & 3); \
    _Pragma("unroll") \
    for (int dy = 0; dy < 3; ++dy) { \
      acc[dy*3+0] = fmaf(w0c, P[dy], acc[dy*3+0]); \
      acc[dy*3+1] = fmaf(w0c, Q[dy], acc[dy*3+1]); \
      acc[dy*3+2] = fmaf(w0c, R[dy], acc[dy*3+2]); \
    } \
    if (ci == 0) rs += w0c; \
  }
#define G4_0(c) { const float4 w0 = *(const float4*)(wr + (c)); \
    STEP((c)+0, Av, Bv, Cv, w0) STEP((c)+1, Bv, Cv, Av, w0) \
    STEP((c)+2, Cv, Av, Bv, w0) STEP((c)+3, Av, Bv, Cv, w0) }
#define G4_1(c) { const float4 w0 = *(const float4*)(wr + (c)); \
    STEP((c)+0, Bv, Cv, Av, w0) STEP((c)+1, Cv, Av, Bv, w0) \
    STEP((c)+2, Av, Bv, Cv, w0) STEP((c)+3, Bv, Cv, Av, w0) }
#define G4_2(c) { const float4 w0 = *(const float4*)(wr + (c)); \
    STEP((c)+0, Cv, Av, Bv, w0) STEP((c)+1, Av, Bv, Cv, w0) \
    STEP((c)+2, Bv, Cv, Av, w0) STEP((c)+3, Cv, Av, Bv, w0) }

      G4_0(0) G4_1(4) G4_2(8) G4_0(12) G4_1(16) G4_2(20) G4_0(24) G4_1(28)

#undef G4_0
#undef G4_1
#undef G4_2
#undef STEP
#undef WCOMP
      REDUCE_WRITE(ci)
    }
  } else {
    constexpr int PER = (S >= 32) ? (S / 32) : 1;   // 8 / 2 / 1
    #pragma unroll
    for (int ci = 0; ci < 3; ++ci) {
      float acc[9];
      #pragma unroll
      for (int j = 0; j < 9; ++j) acc[j] = 0.0f;
      float rs = 0.0f;
      if (S >= 32 || ss < S) {
        #pragma unroll
        for (int u = 0; u < PER; ++u) {
          const int s  = (S >= 32) ? (ss * PER + u) : ss;
          const int yo = s / Wd, xo = s % Wd;
          const float wx = wsrc[s];
          #pragma unroll
          for (int dy = 0; dy < 3; ++dy) {
            const int ba = ci * CHSZ + (yo * STRIDE + dy + 1) * PITCH + (xo * STRIDE + 1);
            #pragma unroll
            for (int dx = 0; dx < 3; ++dx)
              acc[dy * 3 + dx] = fmaf(wx, s_xi[ba + dx], acc[dy * 3 + dx]);
          }
          if (ci == 0) rs += wx;
        }
      }
      REDUCE_WRITE(ci)
    }
  }
#undef REDUCE_WRITE
}

__global__ __launch_bounds__(NTHR, 4)
void ood_a(OodArgs A_) {
  __shared__ __align__(16) float smem[A_SMEM];
  switch (blockIdx.y) {
    case 0:
    case 1:  stageA<1024, 1>(A_, smem, blockIdx.y); break;
    case 2:  stageA< 256, 2>(A_, smem, 2); break;
    case 3:  stageA<  64, 4>(A_, smem, 3); break;
    default: stageA<  16, 8>(A_, smem, 4); break;
  }
}

// ---------------------------------------------------------------------------
// KERNEL B: phases 4a/4b/5 (std, mahal+RNG, argmax, outputs).  R18's exact
// proven form (320 thr, wave g handles classes {g, g+5}); dispatch in LPT
// order (y=0 -> stage 4, C=512 first) so the longest blocks' tail is
// backfilled by the short stages.  Same-stage blocks stay contiguous.
// ---------------------------------------------------------------------------
template<int I, int C>
__device__ __forceinline__ void stageB(const OodArgs& A_, float* smem) {
  const int b = blockIdx.x;
  const int t = threadIdx.x;

  float* s_g   = smem;             // 540
  float* s_rs  = smem + 540;       // 20
  float* s_std = smem + 560;       // 10*C
  float* s_pt  = smem + 560 + 10 * C;  // 10
  int*   s_idx = (int*)(smem + 570 + 10 * C);

  const float* feat_w = A_.feat_w[I];
  const float* feat_b = A_.feat_b[I];
  const uint32_t fk0 = A_.fk0[I], fk1 = A_.fk1[I];

  const float* gsrc = A_.gws + (size_t)(b * 5 + I) * 560;
  for (int p = t; p < 560; p += 320) smem[p] = gsrc[p];
  __syncthreads();

  // ---- phase 4a: s_std[k*C+c] for all classes ----
  for (int v = t; v < 10 * C; v += 320) {
    const int k2 = v / C; const int c = v - k2 * C;
    const float* fw = feat_w + c * 27;
    float a2 = 0.0f;
    #pragma unroll
    for (int j = 0; j < 27; ++j) a2 = fmaf(s_g[(10 + k2) * 27 + j], fw[j], a2);
    a2 = fmaf(feat_b[c], s_rs[10 + k2], a2) + A_.std_b[I][k2];
    s_std[v] = a2;
  }
  __syncthreads();

  // ---- phase 4b: mahal — wave g handles classes {g, g+5}, all lanes ----
  {
    const int g  = t >> 6;     // 0..4
    const int ln = t & 63;
    float m0 = 0.0f, m1 = 0.0f;
    for (int c = ln; c < C; c += 64) {
      {
        const float sd  = s_std[g * C + c];
        const float eps = jax_normal_pt(fk0, fk1, (uint32_t)((b * 10 + g) * C + c));
        m0 = fmaf(sd * sd, eps * eps, m0);
      }
      {
        const float sd  = s_std[(g + 5) * C + c];
        const float eps = jax_normal_pt(fk0, fk1, (uint32_t)((b * 10 + g + 5) * C + c));
        m1 = fmaf(sd * sd, eps * eps, m1);
      }
    }
    #pragma unroll
    for (int off = 32; off > 0; off >>= 1) {
      m0 += __shfl_down(m0, off, 64);
      m1 += __shfl_down(m1, off, 64);
    }
    if (ln == 0) { s_pt[g] = m0; s_pt[g + 5] = m1; }
  }
  __syncthreads();
  if (t == 0) {
    float best = -INFINITY; int bi = 0;
    #pragma unroll
    for (int k2 = 0; k2 < 10; ++k2) {
      float m = -0.5f * s_pt[k2];
      if (m > best) { best = m; bi = k2; }
    }
    A_.scores[b * 5 + I] = best;
    *s_idx = bi;
  }
  __syncthreads();

  // ---- phase 5: outputs (mean recomputed for argmax class; std from LDS) --
  const int idx = *s_idx;
  for (int c = t; c < C; c += 320) {
    const float* fw = feat_w + c * 27;
    float a1 = 0.0f;
    #pragma unroll
    for (int j = 0; j < 27; ++j) a1 = fmaf(s_g[idx * 27 + j], fw[j], a1);
    a1 = fmaf(feat_b[c], s_rs[idx], a1) + A_.mu_b[I][idx];
    A_.mean_out[I][(size_t)b * C + c] = a1;
    A_.std_out[I][(size_t)b * C + c]  = s_std[idx * C + c];
  }
}

__global__ __launch_bounds__(320)
void ood_b(OodArgs A_) {
  __shared__ float smem[571 + 5120];   // worst case C=512
  switch (blockIdx.y) {                // LPT: y=0 -> heaviest stage (C=512)
    case 0: stageB<4, 512>(A_, smem); break;
    case 1: stageB<3, 256>(A_, smem); break;
    case 2: stageB<2, 128>(A_, smem); break;
    case 3: stageB<1,  64>(A_, smem); break;
    default: stageB<0, 64>(A_, smem); break;
  }
}

__global__ void ood_clf(const float* __restrict__ scores,  // (B,5)
                        const float* __restrict__ clf_w,   // (1,5)
                        const float* __restrict__ clf_b,   // (1,)
                        float* __restrict__ out) {         // (B,)
  int b = blockIdx.x * blockDim.x + threadIdx.x;
  if (b < B_SZ) {
    float acc = clf_b[0];
    #pragma unroll
    for (int i = 0; i < 5; ++i) acc = fmaf(scores[b * 5 + i], clf_w[i], acc);
    out[b] = acc;
  }
}

extern "C" void kernel_launch(void* const* d_in, const int* in_sizes, int n_in,
                              void* d_out, int out_size, void* d_ws, size_t ws_size,
                              hipStream_t stream) {
  (void)in_sizes; (void)n_in; (void)out_size; (void)ws_size;
  const float* clf_w = (const float*)d_in[33];
  const float* clf_b = (const float*)d_in[34];
  float* out = (float*)d_out;
  float* ws  = (float*)d_ws;   // scores[5120] | g-blobs[5120*560]

  OodArgs A_;
  A_.x       = (const float*)d_in[0];
  A_.noise_w = (const float*)d_in[1];
  A_.noise_b = (const float*)d_in[2];
  const size_t NMEAN = 1048576;
  const size_t moff[5] = {1024, 66560, 132096, 263168, 525312};
  for (int i = 0; i < 5; ++i) {
    A_.feat_w[i]   = (const float*)d_in[3 + 6 * i];
    A_.feat_b[i]   = (const float*)d_in[4 + 6 * i];
    A_.mu_w[i]     = (const float*)d_in[5 + 6 * i];
    A_.mu_b[i]     = (const float*)d_in[6 + 6 * i];
    A_.std_w[i]    = (const float*)d_in[7 + 6 * i];
    A_.std_b[i]    = (const float*)d_in[8 + 6 * i];
    A_.mean_out[i] = out + moff[i];
    A_.std_out[i]  = out + moff[i] + NMEAN;
    tf2x32(0u, 42u, 0u, (uint32_t)i, A_.fk0[i], A_.fk1[i]);
  }
  A_.scores = ws;
  A_.gws    = ws + 5120;

  ood_a<<<dim3(B_SZ, 5), NTHR, 0, stream>>>(A_);
  ood_b<<<dim3(B_SZ, 5), 320, 0, stream>>>(A_);
  ood_clf<<<(B_SZ + 255) / 256, 256, 0, stream>>>(A_.scores, clf_w, clf_b, out);
}

// Round 21
// 274.995 us; speedup vs baseline: 1.1881x; 1.0132x over previous
//
#include <hip/hip_runtime.h>
#include <cstdint>

#define B_SZ 1024
#define NTHR 640

// ---------------------------------------------------------------------------
// Threefry-2x32 (20 rounds), exactly as jax._src.prng.threefry2x32.
// ---------------------------------------------------------------------------
__host__ __device__ inline void tf2x32(uint32_t k0, uint32_t k1,
                                       uint32_t x0, uint32_t x1,
                                       uint32_t& o0, uint32_t& o1) {
  uint32_t ks2 = 0x1BD11BDAu ^ k0 ^ k1;
#define TF_RND(r) { x0 += x1; x1 = (x1 << (r)) | (x1 >> (32 - (r))); x1 ^= x0; }
  x0 += k0; x1 += k1;
  TF_RND(13) TF_RND(15) TF_RND(26) TF_RND(6)
  x0 += k1; x1 += ks2 + 1u;
  TF_RND(17) TF_RND(29) TF_RND(16) TF_RND(24)
  x0 += ks2; x1 += k0 + 2u;
  TF_RND(13) TF_RND(15) TF_RND(26) TF_RND(6)
  x0 += k0; x1 += k1 + 3u;
  TF_RND(17) TF_RND(29) TF_RND(16) TF_RND(24)
  x0 += k1; x1 += ks2 + 4u;
  TF_RND(13) TF_RND(15) TF_RND(26) TF_RND(6)
  x0 += ks2; x1 += k0 + 5u;
#undef TF_RND
  o0 = x0; o1 = x1;
}

// XLA ErfInv f32 expansion, identical coefficients.
__device__ inline float erfinv_f32(float x) {
  float w = -log1pf(-x * x);
  float p;
  if (w < 5.0f) {
    w -= 2.5f;
    p = 2.81022636e-08f;
    p = fmaf(p, w, 3.43273939e-07f);
    p = fmaf(p, w, -3.5233877e-06f);
    p = fmaf(p, w, -4.39150654e-06f);
    p = fmaf(p, w, 0.00021858087f);
    p = fmaf(p, w, -0.00125372503f);
    p = fmaf(p, w, -0.00417768164f);
    p = fmaf(p, w, 0.246640727f);
    p = fmaf(p, w, 1.50140941f);
  } else {
    w = sqrtf(w) - 3.0f;
    p = -0.000200214257f;
    p = fmaf(p, w, 0.000100950558f);
    p = fmaf(p, w, 0.00134934322f);
    p = fmaf(p, w, -0.00367342844f);
    p = fmaf(p, w, 0.00573950773f);
    p = fmaf(p, w, -0.0076224613f);
    p = fmaf(p, w, 0.00943887047f);
    p = fmaf(p, w, 1.00167406f);
    p = fmaf(p, w, 2.83297682f);
  }
  return p * x;
}

__device__ inline float jax_normal_pt(uint32_t k0, uint32_t k1, uint32_t e) {
  uint32_t o0, o1;
  tf2x32(k0, k1, 0u, e, o0, o1);
  uint32_t bits = o0 ^ o1;
  float f = __uint_as_float((bits >> 9) | 0x3f800000u) - 1.0f;
  const float LO = -0.99999994f;
  float u = fmaxf(LO, fmaf(f, 2.0f, LO));
  return 1.41421356f * erfinv_f32(u);
}

struct OodArgs {
  const float* x;
  const float* noise_w;
  const float* noise_b;
  const float* feat_w[5];
  const float* feat_b[5];
  const float* mu_w[5];
  const float* mu_b[5];
  const float* std_w[5];
  const float* std_b[5];
  float* mean_out[5];
  float* std_out[5];
  float* scores;   // ws[0..5120)
  float* gws;      // ws + 5120: per (b,I) 560 floats: g[540] | rs[20]
  uint32_t fk0[5], fk1[5];
};

// Padded image buffers: 34 rows x pitch 35 per channel.  Phase-3 lane banks:
// addr = 35*ss + c -> bank 3*ss mod 32, all-distinct for ss in [0,32).
#define PITCH 35
#define CHSZ  (34 * PITCH)   // 1190
#define XSZ   (3 * CHSZ)     // 3570

// Kernel A LDS (floats)
#define A_XP   0             // 3570
#define A_XI   3570          // 3570
#define A_NW   7140          // 81
#define A_NB   7221          // 3
#define A_SMEM 7224

// ---------------------------------------------------------------------------
// KERNEL A (phases 1-3): 640 thr = 20 groups x 32 lanes, 1 row + 1 k per
// lane, b32 conflict-free; phase 2 register-staged (zero bank conflicts,
// R17); launch bounds (640,4) -> no spill (R18).  Split into s1/sN kernels
// (specialized regalloc; R20's merged form cost +50us), grouped y-major
// grids keep same-stage blocks contiguous (R19 I-cache lesson).
// ---------------------------------------------------------------------------
template<int S, int STRIDE>
__device__ __forceinline__ void stageA(const OodArgs& A_, float* smem, int i) {
  constexpr int Wd = 32 / STRIDE;
  const int b = blockIdx.x;
  const int t = threadIdx.x;

  float* s_xp = smem + A_XP;
  float* s_xi = smem + A_XI;
  float* s_nw = smem + A_NW;
  float* s_nb = smem + A_NB;

  // ---- phase 1: zero padded buffers (float4), load x[b] interior ----
  {
    float4 z; z.x = z.y = z.z = z.w = 0.0f;
    float4* z4 = (float4*)smem;                  // smem is 16B-aligned
    for (int p = t; p < (2 * XSZ) / 4; p += NTHR) z4[p] = z;
  }
  if (t < 81) s_nw[t] = A_.noise_w[81 * i + t];
  if (t < 3)  s_nb[t] = A_.noise_b[3 * i + t];
  __syncthreads();
  const float* xb = A_.x + (size_t)b * 3072;
  for (int p = t; p < 3072; p += NTHR) {
    int ci = p >> 10, rr = p & 1023, yy = rr >> 5, xx = rr & 31;
    s_xp[ci * CHSZ + (yy + 1) * PITCH + (xx + 1)] = xb[p];
  }
  __syncthreads();

  // ---- phase 2: xi = x + conv3x3(x, noise_w); 384 threads x 8-px runs ----
  if (t < 384) {
    const int co = t >> 7;            // 0..2
    const int r  = t & 127;
    const int y  = r >> 2;            // 0..31
    const int xs = (r & 3) * 8;       // 0,8,16,24
    const float nb = s_nb[co];
    float acc[8];
    #pragma unroll
    for (int j = 0; j < 8; ++j) acc[j] = nb;
    #pragma unroll
    for (int c2 = 0; c2 < 3; ++c2) {
      #pragma unroll
      for (int dy = 0; dy < 3; ++dy) {
        const float w0 = s_nw[co * 27 + c2 * 9 + dy * 3 + 0];
        const float w1 = s_nw[co * 27 + c2 * 9 + dy * 3 + 1];
        const float w2 = s_nw[co * 27 + c2 * 9 + dy * 3 + 2];
        const int ra = c2 * CHSZ + (y + dy) * PITCH + xs;
        float R[10];
        #pragma unroll
        for (int u = 0; u < 10; ++u) R[u] = s_xp[ra + u];
        #pragma unroll
        for (int j = 0; j < 8; ++j) {
          acc[j] = fmaf(w0, R[j],     acc[j]);
          acc[j] = fmaf(w1, R[j + 1], acc[j]);
          acc[j] = fmaf(w2, R[j + 2], acc[j]);
        }
      }
    }
    const int ob = co * CHSZ + (y + 1) * PITCH + (xs + 1);
    #pragma unroll
    for (int j = 0; j < 8; ++j)
      s_xi[ob + j] = acc[j] + s_xp[ob + j];
  }
  __syncthreads();

  // ---- phase 3: g[wh][k][ci*9+q] = sum_s w[k,s]*xi[ci,patch(s,q)] ----
  const int G  = t >> 5;           // 0..19
  const int ss = t & 31;           // row / spatial sub
  const int wh = G & 1;
  const int kk = G >> 1;           // 0..9
  const float* wsrc = (wh ? A_.std_w[i] : A_.mu_w[i]) + kk * S;
  float* gdst = A_.gws + (size_t)(b * 5 + i) * 560;

#define REDUCE_WRITE(ci_) { \
    _Pragma("unroll") \
    for (int j = 0; j < 9; ++j) { \
      float v = acc[j]; \
      v += __shfl_xor(v,  1, 64); \
      v += __shfl_xor(v,  2, 64); \
      v += __shfl_xor(v,  4, 64); \
      v += __shfl_xor(v,  8, 64); \
      v += __shfl_xor(v, 16, 64); \
      acc[j] = v; \
    } \
    if ((ci_) == 0) { \
      rs += __shfl_xor(rs, 1, 64); rs += __shfl_xor(rs, 2, 64); \
      rs += __shfl_xor(rs, 4, 64); rs += __shfl_xor(rs, 8, 64); \
      rs += __shfl_xor(rs, 16, 64); \
    } \
    if (ss == 0) { \
      _Pragma("unroll") \
      for (int j = 0; j < 9; ++j) \
        gdst[(wh * 10 + kk) * 27 + (ci_) * 9 + j] = acc[j]; \
      if ((ci_) == 0) gdst[540 + wh * 10 + kk] = rs; \
    } }

  if constexpr (STRIDE == 1) {
    // lane owns output row ss; padded rows ss..ss+2 at rb + u*PITCH.
    const float* wr = wsrc + ss * 32;
    const int rbase0 = ss * PITCH;
    #pragma unroll
    for (int ci = 0; ci < 3; ++ci) {
      const int rb = ci * CHSZ + rbase0;
      float acc[9];
      #pragma unroll
      for (int j = 0; j < 9; ++j) acc[j] = 0.0f;
      float rs = 0.0f;
      float Av[3], Bv[3], Cv[3];
      #pragma unroll
      for (int u = 0; u < 3; ++u) {
        Av[u] = s_xi[rb + u * PITCH + 0];
        Bv[u] = s_xi[rb + u * PITCH + 1];
      }

#define WCOMP(V, L) ((L) == 0 ? (V).x : (L) == 1 ? (V).y : (L) == 2 ? (V).z : (V).w)
#define STEP(X, P, Q, R, W0) { \
    _Pragma("unroll") \
    for (int u = 0; u < 3; ++u) R[u] = s_xi[rb + u * PITCH + (X) + 2]; \
    const float w0c = WCOMP(W0, (X) & 3); \
    _Pragma("unroll") \
    for (int dy = 0; dy < 3; ++dy) { \
      acc[dy*3+0] = fmaf(w0c, P[dy], acc[dy*3+0]); \
      acc[dy*3+1] = fmaf(w0c, Q[dy], acc[dy*3+1]); \
      acc[dy*3+2] = fmaf(w0c, R[dy], acc[dy*3+2]); \
    } \
    if (ci == 0) rs += w0c; \
  }
#define G4_0(c) { const float4 w0 = *(const float4*)(wr + (c)); \
    STEP((c)+0, Av, Bv, Cv, w0) STEP((c)+1, Bv, Cv, Av, w0) \
    STEP((c)+2, Cv, Av, Bv, w0) STEP((c)+3, Av, Bv, Cv, w0) }
#define G4_1(c) { const float4 w0 = *(const float4*)(wr + (c)); \
    STEP((c)+0, Bv, Cv, Av, w0) STEP((c)+1, Cv, Av, Bv, w0) \
    STEP((c)+2, Av, Bv, Cv, w0) STEP((c)+3, Bv, Cv, Av, w0) }
#define G4_2(c) { const float4 w0 = *(const float4*)(wr + (c)); \
    STEP((c)+0, Cv, Av, Bv, w0) STEP((c)+1, Av, Bv, Cv, w0) \
    STEP((c)+2, Bv, Cv, Av, w0) STEP((c)+3, Cv, Av, Bv, w0) }

      G4_0(0) G4_1(4) G4_2(8) G4_0(12) G4_1(16) G4_2(20) G4_0(24) G4_1(28)

#undef G4_0
#undef G4_1
#undef G4_2
#undef STEP
#undef WCOMP
      REDUCE_WRITE(ci)
    }
  } else {
    constexpr int PER = (S >= 32) ? (S / 32) : 1;   // 8 / 2 / 1
    #pragma unroll
    for (int ci = 0; ci < 3; ++ci) {
      float acc[9];
      #pragma unroll
      for (int j = 0; j < 9; ++j) acc[j] = 0.0f;
      float rs = 0.0f;
      if (S >= 32 || ss < S) {
        #pragma unroll
        for (int u = 0; u < PER; ++u) {
          const int s  = (S >= 32) ? (ss * PER + u) : ss;
          const int yo = s / Wd, xo = s % Wd;
          const float wx = wsrc[s];
          #pragma unroll
          for (int dy = 0; dy < 3; ++dy) {
            const int ba = ci * CHSZ + (yo * STRIDE + dy + 1) * PITCH + (xo * STRIDE + 1);
            #pragma unroll
            for (int dx = 0; dx < 3; ++dx)
              acc[dy * 3 + dx] = fmaf(wx, s_xi[ba + dx], acc[dy * 3 + dx]);
          }
          if (ci == 0) rs += wx;
        }
      }
      REDUCE_WRITE(ci)
    }
  }
#undef REDUCE_WRITE
}

__global__ __launch_bounds__(NTHR, 4)
void ood_a_s1(OodArgs A_) {
  __shared__ __align__(16) float smem[A_SMEM];
  stageA<1024, 1>(A_, smem, blockIdx.y);          // stages 0,1 (y-major)
}

__global__ __launch_bounds__(NTHR, 4)
void ood_a_sN(OodArgs A_) {
  __shared__ __align__(16) float smem[A_SMEM];
  switch (blockIdx.y) {
    case 0:  stageA<256, 2>(A_, smem, 2); break;
    case 1:  stageA< 64, 4>(A_, smem, 3); break;
    default: stageA< 16, 8>(A_, smem, 4); break;
  }
}

// ---------------------------------------------------------------------------
// KERNEL B: phases 4a/4b/5 (std, mahal+RNG, argmax, outputs).  R18's proven
// 320-thread form; LPT dispatch order (y=0 -> C=512 first) so the longest
// blocks' tail is backfilled by the short stages (R20: 131 -> ~62 us).
// ---------------------------------------------------------------------------
template<int I, int C>
__device__ __forceinline__ void stageB(const OodArgs& A_, float* smem) {
  const int b = blockIdx.x;
  const int t = threadIdx.x;

  float* s_g   = smem;             // 540
  float* s_rs  = smem + 540;       // 20
  float* s_std = smem + 560;       // 10*C
  float* s_pt  = smem + 560 + 10 * C;  // 10
  int*   s_idx = (int*)(smem + 570 + 10 * C);

  const float* feat_w = A_.feat_w[I];
  const float* feat_b = A_.feat_b[I];
  const uint32_t fk0 = A_.fk0[I], fk1 = A_.fk1[I];

  const float* gsrc = A_.gws + (size_t)(b * 5 + I) * 560;
  for (int p = t; p < 560; p += 320) smem[p] = gsrc[p];
  __syncthreads();

  // ---- phase 4a: s_std[k*C+c] for all classes ----
  for (int v = t; v < 10 * C; v += 320) {
    const int k2 = v / C; const int c = v - k2 * C;
    const float* fw = feat_w + c * 27;
    float a2 = 0.0f;
    #pragma unroll
    for (int j = 0; j < 27; ++j) a2 = fmaf(s_g[(10 + k2) * 27 + j], fw[j], a2);
    a2 = fmaf(feat_b[c], s_rs[10 + k2], a2) + A_.std_b[I][k2];
    s_std[v] = a2;
  }
  __syncthreads();

  // ---- phase 4b: mahal — wave g handles classes {g, g+5}, all lanes ----
  {
    const int g  = t >> 6;     // 0..4
    const int ln = t & 63;
    float m0 = 0.0f, m1 = 0.0f;
    for (int c = ln; c < C; c += 64) {
      {
        const float sd  = s_std[g * C + c];
        const float eps = jax_normal_pt(fk0, fk1, (uint32_t)((b * 10 + g) * C + c));
        m0 = fmaf(sd * sd, eps * eps, m0);
      }
      {
        const float sd  = s_std[(g + 5) * C + c];
        const float eps = jax_normal_pt(fk0, fk1, (uint32_t)((b * 10 + g + 5) * C + c));
        m1 = fmaf(sd * sd, eps * eps, m1);
      }
    }
    #pragma unroll
    for (int off = 32; off > 0; off >>= 1) {
      m0 += __shfl_down(m0, off, 64);
      m1 += __shfl_down(m1, off, 64);
    }
    if (ln == 0) { s_pt[g] = m0; s_pt[g + 5] = m1; }
  }
  __syncthreads();
  if (t == 0) {
    float best = -INFINITY; int bi = 0;
    #pragma unroll
    for (int k2 = 0; k2 < 10; ++k2) {
      float m = -0.5f * s_pt[k2];
      if (m > best) { best = m; bi = k2; }
    }
    A_.scores[b * 5 + I] = best;
    *s_idx = bi;
  }
  __syncthreads();

  // ---- phase 5: outputs (mean recomputed for argmax class; std from LDS) --
  const int idx = *s_idx;
  for (int c = t; c < C; c += 320) {
    const float* fw = feat_w + c * 27;
    float a1 = 0.0f;
    #pragma unroll
    for (int j = 0; j < 27; ++j) a1 = fmaf(s_g[idx * 27 + j], fw[j], a1);
    a1 = fmaf(feat_b[c], s_rs[idx], a1) + A_.mu_b[I][idx];
    A_.mean_out[I][(size_t)b * C + c] = a1;
    A_.std_out[I][(size_t)b * C + c]  = s_std[idx * C + c];
  }
}

__global__ __launch_bounds__(320)
void ood_b(OodArgs A_) {
  __shared__ float smem[571 + 5120];   // worst case C=512
  switch (blockIdx.y) {                // LPT: y=0 -> heaviest stage (C=512)
    case 0: stageB<4, 512>(A_, smem); break;
    case 1: stageB<3, 256>(A_, smem); break;
    case 2: stageB<2, 128>(A_, smem); break;
    case 3: stageB<1,  64>(A_, smem); break;
    default: stageB<0, 64>(A_, smem); break;
  }
}

__global__ void ood_clf(const float* __restrict__ scores,  // (B,5)
                        const float* __restrict__ clf_w,   // (1,5)
                        const float* __restrict__ clf_b,   // (1,)
                        float* __restrict__ out) {         // (B,)
  int b = blockIdx.x * blockDim.x + threadIdx.x;
  if (b < B_SZ) {
    float acc = clf_b[0];
    #pragma unroll
    for (int i = 0; i < 5; ++i) acc = fmaf(scores[b * 5 + i], clf_w[i], acc);
    out[b] = acc;
  }
}

extern "C" void kernel_launch(void* const* d_in, const int* in_sizes, int n_in,
                              void* d_out, int out_size, void* d_ws, size_t ws_size,
                              hipStream_t stream) {
  (void)in_sizes; (void)n_in; (void)out_size; (void)ws_size;
  const float* clf_w = (const float*)d_in[33];
  const float* clf_b = (const float*)d_in[34];
  float* out = (float*)d_out;
  float* ws  = (float*)d_ws;   // scores[5120] | g-blobs[5120*560]

  OodArgs A_;
  A_.x       = (const float*)d_in[0];
  A_.noise_w = (const float*)d_in[1];
  A_.noise_b = (const float*)d_in[2];
  const size_t NMEAN = 1048576;
  const size_t moff[5] = {1024, 66560, 132096, 263168, 525312};
  for (int i = 0; i < 5; ++i) {
    A_.feat_w[i]   = (const float*)d_in[3 + 6 * i];
    A_.feat_b[i]   = (const float*)d_in[4 + 6 * i];
    A_.mu_w[i]     = (const float*)d_in[5 + 6 * i];
    A_.mu_b[i]     = (const float*)d_in[6 + 6 * i];
    A_.std_w[i]    = (const float*)d_in[7 + 6 * i];
    A_.std_b[i]    = (const float*)d_in[8 + 6 * i];
    A_.mean_out[i] = out + moff[i];
    A_.std_out[i]  = out + moff[i] + NMEAN;
    tf2x32(0u, 42u, 0u, (uint32_t)i, A_.fk0[i], A_.fk1[i]);
  }
  A_.scores = ws;
  A_.gws    = ws + 5120;

  ood_a_s1<<<dim3(B_SZ, 2), NTHR, 0, stream>>>(A_);
  ood_a_sN<<<dim3(B_SZ, 3), NTHR, 0, stream>>>(A_);
  ood_b<<<dim3(B_SZ, 5), 320, 0, stream>>>(A_);
  ood_clf<<<(B_SZ + 255) / 256, 256, 0, stream>>>(A_.scores, clf_w, clf_b, out);
}